// Round 2
// baseline (732.596 us; speedup 1.0000x reference)
//
#include <hip/hip_runtime.h>
#include <hip/hip_bf16.h>
#include <stdint.h>

#define S_LEN 2048
#define HIDDEN 3584
#define NHEAD 16
#define NKVH 8
#define HDIM 256
#define QKV_N 8192
#define AO_N 4096
#define WINLEN 1024

typedef __attribute__((ext_vector_type(8))) short bf16x8;
typedef __attribute__((ext_vector_type(4))) float f32x4;

__device__ __forceinline__ void async_cp16(const void* g, void* l) {
  __builtin_amdgcn_global_load_lds(
      (const __attribute__((address_space(1))) void*)g,
      (__attribute__((address_space(3))) void*)l, 16, 0, 0);
}

__device__ __forceinline__ float fast_exp2(float x) {
#if __has_builtin(__builtin_amdgcn_exp2f)
  return __builtin_amdgcn_exp2f(x);
#else
  return __exp2f(x);
#endif
}
__device__ __forceinline__ float fast_rcp(float x) {
#if __has_builtin(__builtin_amdgcn_rcpf)
  return __builtin_amdgcn_rcpf(x);
#else
  return 1.0f / x;
#endif
}

__device__ __forceinline__ unsigned short f2bf(float f) {
  unsigned u = __float_as_uint(f);
  u += 0x7FFF + ((u >> 16) & 1);
  return (unsigned short)(u >> 16);
}
__device__ __forceinline__ float bf2f(unsigned short h) {
  return __uint_as_float(((unsigned)h) << 16);
}

// ---------------- elementwise f32 -> bf16 cast (vectorized) ----------------
__global__ void k_cast_bf16(const float* __restrict__ in,
                            unsigned short* __restrict__ out, int n4) {
  int i = blockIdx.x * blockDim.x + threadIdx.x;
  int stride = gridDim.x * blockDim.x;
  for (; i < n4; i += stride) {
    float4 v = ((const float4*)in)[i];
    uint2 o;
    o.x = (unsigned)f2bf(v.x) | ((unsigned)f2bf(v.y) << 16);
    o.y = (unsigned)f2bf(v.z) | ((unsigned)f2bf(v.w) << 16);
    ((uint2*)out)[i] = o;
  }
}

// ------------- transpose + convert: f32 [R][C] -> bf16 [C][R] -------------
__global__ void k_transpose_bf16(const float* __restrict__ in,
                                 unsigned short* __restrict__ out,
                                 int R, int C) {
  __shared__ float tile[64][65];
  int c0 = blockIdx.x * 64, r0 = blockIdx.y * 64;
  int t = threadIdx.x;
#pragma unroll
  for (int j = 0; j < 16; ++j) {
    int idx = t + j * 256;
    int rl = idx >> 6, cl = idx & 63;
    tile[rl][cl] = in[(size_t)(r0 + rl) * C + c0 + cl];
  }
  __syncthreads();
#pragma unroll
  for (int j = 0; j < 16; ++j) {
    int idx = t + j * 256;
    int cl = idx >> 6, rl = idx & 63;
    out[(size_t)(c0 + cl) * R + r0 + rl] = f2bf(tile[rl][cl]);
  }
}

// ---------------- bf16 GEMM: C[M][N] = A[M][K] * B^T, B stored [N][K] -----
// 128x128 tile, BK=64, 4 waves (2x2), 16x16x32 MFMA, global_load_lds + swizzle
template <bool OUT_BF16>
__global__ __launch_bounds__(256, 2) void k_gemm(
    const unsigned short* __restrict__ A, const unsigned short* __restrict__ B,
    void* __restrict__ Cout, int M, int N, int K) {
  __shared__ unsigned short sA[2][128 * 64];
  __shared__ unsigned short sB[2][128 * 64];
  const int t = threadIdx.x;
  const int lane = t & 63;
  const int wid = t >> 6;
  const int m0 = blockIdx.y * 128;
  const int n0 = blockIdx.x * 128;
  const int wr = wid >> 1, wc = wid & 1;
  const int lrow = lane & 15, lgrp = lane >> 4;

  f32x4 acc[4][4] = {};

  const int lr = lane >> 3;                    // 0..7  (row within 8-row group)
  const int sw = (lane & 7) ^ (lr & 7);        // swizzled logical chunk

  const int NT = K >> 6;

  auto stage = [&](int buf, int kt) {
    const int klo = kt * 64;
#pragma unroll
    for (int i = 0; i < 4; ++i) {
      int r = wid * 32 + i * 8 + lr;
      async_cp16(A + (size_t)(m0 + r) * K + klo + sw * 8,
                 &sA[buf][(wid * 32 + i * 8) * 64]);
    }
#pragma unroll
    for (int i = 0; i < 4; ++i) {
      int r = wid * 32 + i * 8 + lr;
      async_cp16(B + (size_t)(n0 + r) * K + klo + sw * 8,
                 &sB[buf][(wid * 32 + i * 8) * 64]);
    }
  };

  stage(0, 0);
  for (int kt = 0; kt < NT; ++kt) {
    int cur = kt & 1;
    __syncthreads();  // drains vmcnt(0): current buffer ready, other buffer free
    if (kt + 1 < NT) stage(cur ^ 1, kt + 1);
#pragma unroll
    for (int kk = 0; kk < 2; ++kk) {
      bf16x8 af[4], bfr[4];
#pragma unroll
      for (int m = 0; m < 4; ++m) {
        int r = wr * 64 + m * 16 + lrow;
        int c = (kk * 4 + lgrp) ^ (r & 7);
        af[m] = *(const bf16x8*)&sA[cur][r * 64 + c * 8];
      }
#pragma unroll
      for (int n = 0; n < 4; ++n) {
        int r = wc * 64 + n * 16 + lrow;
        int c = (kk * 4 + lgrp) ^ (r & 7);
        bfr[n] = *(const bf16x8*)&sB[cur][r * 64 + c * 8];
      }
#pragma unroll
      for (int m = 0; m < 4; ++m)
#pragma unroll
        for (int n = 0; n < 4; ++n)
          acc[m][n] = __builtin_amdgcn_mfma_f32_16x16x32_bf16(
              af[m], bfr[n], acc[m][n], 0, 0, 0);
    }
  }
#pragma unroll
  for (int m = 0; m < 4; ++m) {
    int row_b = m0 + wr * 64 + m * 16 + lgrp * 4;
#pragma unroll
    for (int n = 0; n < 4; ++n) {
      int col = n0 + wc * 64 + n * 16 + lrow;
#pragma unroll
      for (int r = 0; r < 4; ++r) {
        int row = row_b + r;
        if constexpr (OUT_BF16)
          ((unsigned short*)Cout)[(size_t)row * N + col] = f2bf(acc[m][n][r]);
        else
          ((float*)Cout)[(size_t)row * N + col] = acc[m][n][r];
      }
    }
  }
}

// ---------------- RoPE + layout: qkv[2048][8192] -> Q, K (roped), V^T -----
__global__ void k_rope_layout(const unsigned short* __restrict__ qkv,
                              const float* __restrict__ fcos,
                              const float* __restrict__ fsin,
                              unsigned short* __restrict__ Q,
                              unsigned short* __restrict__ K,
                              unsigned short* __restrict__ VT) {
  int s0 = blockIdx.x * 64;
  int y = blockIdx.y;
  int t = threadIdx.x;
  if (y < 24) {
    int colb = (y < 16) ? y * 256 : 4096 + (y - 16) * 256;
    unsigned short* out =
        (y < 16) ? (Q + (size_t)y * S_LEN * HDIM)
                 : (K + (size_t)(y - 16) * S_LEN * HDIM);
#pragma unroll 4
    for (int j = 0; j < 32; ++j) {
      int idx = t + j * 256;
      int sl = idx >> 7;
      int d = idx & 127;
      int s = s0 + sl;
      float x1 = bf2f(qkv[(size_t)s * QKV_N + colb + d]);
      float x2 = bf2f(qkv[(size_t)s * QKV_N + colb + d + 128]);
      float c = fcos[s * 128 + d], sn = fsin[s * 128 + d];
      out[(size_t)s * HDIM + d] = f2bf(x1 * c - x2 * sn);
      out[(size_t)s * HDIM + d + 128] = f2bf(x1 * sn + x2 * c);
    }
  } else {
    int kh = y - 24;
    __shared__ unsigned short tile[64][258];
#pragma unroll 4
    for (int j = 0; j < 64; ++j) {
      int idx = t + j * 256;
      int sl = idx >> 8;
      int d = idx & 255;
      tile[sl][d] = qkv[(size_t)(s0 + sl) * QKV_N + 6144 + kh * 256 + d];
    }
    __syncthreads();
#pragma unroll 4
    for (int j = 0; j < 64; ++j) {
      int idx = t + j * 256;
      int d = idx >> 6;
      int sl = idx & 63;
      VT[(size_t)kh * HDIM * S_LEN + (size_t)d * S_LEN + s0 + sl] = tile[sl][d];
    }
  }
}

// ---------------- windowed softcap attention --------------------------------
// Fixed softmax offset: post-softcap scores bounded by +/-50 -> exp(s-50).
__global__ __launch_bounds__(256) void k_attn(
    const unsigned short* __restrict__ Q,   // [16][2048][256]
    const unsigned short* __restrict__ K,   // [8][2048][256]
    const unsigned short* __restrict__ VT,  // [8][256][2048]
    unsigned short* __restrict__ O) {       // [2048][4096]
  __shared__ unsigned short sP[4][16 * 48];
  int t = threadIdx.x, lane = t & 63, w = t >> 6;
  int h = blockIdx.y;
  int r0 = blockIdx.x * 64 + w * 16;
  const unsigned short* Qh = Q + (size_t)h * S_LEN * HDIM;
  const unsigned short* Kh = K + (size_t)(h >> 1) * S_LEN * HDIM;
  const unsigned short* Vh = VT + (size_t)(h >> 1) * HDIM * S_LEN;
  const int lrow = lane & 15, lgrp = lane >> 4;

  bf16x8 qf[8];
#pragma unroll
  for (int dc = 0; dc < 8; ++dc)
    qf[dc] = *(const bf16x8*)&Qh[(size_t)(r0 + lrow) * HDIM + dc * 32 + lgrp * 8];

  f32x4 zero4 = {0.f, 0.f, 0.f, 0.f};
  f32x4 o[16];
#pragma unroll
  for (int i = 0; i < 16; ++i) o[i] = zero4;
  float psum[4] = {0.f, 0.f, 0.f, 0.f};

  int klo = r0 - (WINLEN - 1);
  if (klo < 0) klo = 0;
  klo &= ~31;
  const float c_pre = 0.0625f / 50.0f;           // SCALING / SOFTCAP
  const float c_2l2e = 2.8853900817779268f;      // 2*log2(e)
  const float c_l2e = 1.4426950408889634f;
  unsigned short* myP = sP[w];

  for (int k0 = klo; k0 <= r0 + 15; k0 += 32) {
#pragma unroll
    for (int st = 0; st < 2; ++st) {
      int ks = k0 + st * 16;
      f32x4 s = zero4;
#pragma unroll
      for (int dc = 0; dc < 8; ++dc) {
        bf16x8 kf =
            *(const bf16x8*)&Kh[(size_t)(ks + lrow) * HDIM + dc * 32 + lgrp * 8];
        s = __builtin_amdgcn_mfma_f32_16x16x32_bf16(qf[dc], kf, s, 0, 0, 0);
      }
#pragma unroll
      for (int r = 0; r < 4; ++r) {
        int q = r0 + lgrp * 4 + r;
        int k = ks + lrow;
        float tt = s[r] * c_pre;
        tt = fminf(fmaxf(tt, -10.f), 10.f);
        float z = fast_exp2(tt * c_2l2e);
        float sc = (z - 1.f) * fast_rcp(z + 1.f) * 50.f;
        float p = 0.f;
        if (k <= q && (q - k) < WINLEN)
          p = fast_exp2((sc - 50.f) * c_l2e);
        unsigned short pb = f2bf(p);
        psum[r] += bf2f(pb);
        myP[(lgrp * 4 + r) * 48 + st * 16 + lrow] = pb;
      }
    }
    bf16x8 pf = *(const bf16x8*)&myP[lrow * 48 + lgrp * 8];
#pragma unroll
    for (int dt = 0; dt < 16; ++dt) {
      bf16x8 vf =
          *(const bf16x8*)&Vh[(size_t)(dt * 16 + lrow) * S_LEN + k0 + lgrp * 8];
      o[dt] = __builtin_amdgcn_mfma_f32_16x16x32_bf16(pf, vf, o[dt], 0, 0, 0);
    }
  }
#pragma unroll
  for (int r = 0; r < 4; ++r) {
    float v = psum[r];
    v += __shfl_xor(v, 1);
    v += __shfl_xor(v, 2);
    v += __shfl_xor(v, 4);
    v += __shfl_xor(v, 8);
    psum[r] = 1.0f / v;
  }
#pragma unroll
  for (int dt = 0; dt < 16; ++dt)
#pragma unroll
    for (int r = 0; r < 4; ++r) {
      int row = r0 + lgrp * 4 + r;
      O[(size_t)row * AO_N + h * HDIM + dt * 16 + lrow] =
          f2bf(o[dt][r] * psum[r]);
    }
}

extern "C" void kernel_launch(void* const* d_in, const int* in_sizes, int n_in,
                              void* d_out, int out_size, void* d_ws,
                              size_t ws_size, hipStream_t stream) {
  const float* hidden = (const float*)d_in[0];
  const float* Wqkv = (const float*)d_in[1];
  const float* Wo = (const float*)d_in[2];
  const float* fcos = (const float*)d_in[3];
  const float* fsin = (const float*)d_in[4];
  float* out = (float*)d_out;
  char* ws = (char*)d_ws;

  // workspace layout (bytes):
  // [0, 58720256)          WqkvT bf16 [8192][3584]; reused later for Q/K/VT
  // [58720256, 73400320)   hidden bf16 [2048][3584]
  // [73400320, 106954752)  qkv bf16 [2048][8192]; reused later for AttnOut
  // [106954752, 136314880) WoT bf16 [3584][4096]
  unsigned short* WqkvT = (unsigned short*)(ws + 0);
  unsigned short* hb = (unsigned short*)(ws + 58720256);
  unsigned short* qkv = (unsigned short*)(ws + 73400320);
  unsigned short* WoT = (unsigned short*)(ws + 106954752);
  unsigned short* Qb = WqkvT;                           // [16][2048][256]
  unsigned short* Kb = WqkvT + (size_t)16 * 2048 * 256; // [8][2048][256]
  unsigned short* VTb = WqkvT + (size_t)24 * 2048 * 256;// [8][256][2048]
  unsigned short* AO = qkv;                             // [2048][4096]

  k_cast_bf16<<<1024, 256, 0, stream>>>(hidden, hb, (2048 * 3584) / 4);
  k_transpose_bf16<<<dim3(8192 / 64, 3584 / 64), 256, 0, stream>>>(
      Wqkv, WqkvT, 3584, 8192);
  k_transpose_bf16<<<dim3(3584 / 64, 4096 / 64), 256, 0, stream>>>(
      Wo, WoT, 4096, 3584);
  k_gemm<true><<<dim3(64, 16), 256, 0, stream>>>(hb, WqkvT, qkv, 2048, 8192,
                                                 3584);
  k_rope_layout<<<dim3(32, 32), 256, 0, stream>>>(qkv, fcos, fsin, Qb, Kb, VTb);
  k_attn<<<dim3(32, 16), 256, 0, stream>>>(Qb, Kb, VTb, AO);
  k_gemm<false><<<dim3(28, 16), 256, 0, stream>>>(AO, WoT, out, 2048, 3584,
                                                  4096);
}

// Round 4
// 732.031 us; speedup vs baseline: 1.0008x; 1.0008x over previous
//
#include <hip/hip_runtime.h>
#include <hip/hip_bf16.h>
#include <stdint.h>

#define S_LEN 2048
#define HIDDEN 3584
#define NHEAD 16
#define NKVH 8
#define HDIM 256
#define QKV_N 8192
#define AO_N 4096
#define WINLEN 1024

typedef __attribute__((ext_vector_type(8))) short bf16x8;
typedef __attribute__((ext_vector_type(4))) float f32x4;

__device__ __forceinline__ void async_cp16(const void* g, void* l) {
  __builtin_amdgcn_global_load_lds(
      (const __attribute__((address_space(1))) void*)g,
      (__attribute__((address_space(3))) void*)l, 16, 0, 0);
}

__device__ __forceinline__ float fast_exp2(float x) {
#if __has_builtin(__builtin_amdgcn_exp2f)
  return __builtin_amdgcn_exp2f(x);
#else
  return __exp2f(x);
#endif
}
__device__ __forceinline__ float fast_rcp(float x) {
#if __has_builtin(__builtin_amdgcn_rcpf)
  return __builtin_amdgcn_rcpf(x);
#else
  return 1.0f / x;
#endif
}

__device__ __forceinline__ unsigned short f2bf(float f) {
  unsigned u = __float_as_uint(f);
  u += 0x7FFF + ((u >> 16) & 1);
  return (unsigned short)(u >> 16);
}
__device__ __forceinline__ float bf2f(unsigned short h) {
  return __uint_as_float(((unsigned)h) << 16);
}

// ---------------- elementwise f32 -> bf16 cast (vectorized) ----------------
__global__ void k_cast_bf16(const float* __restrict__ in,
                            unsigned short* __restrict__ out, int n4) {
  int i = blockIdx.x * blockDim.x + threadIdx.x;
  int stride = gridDim.x * blockDim.x;
  for (; i < n4; i += stride) {
    float4 v = ((const float4*)in)[i];
    uint2 o;
    o.x = (unsigned)f2bf(v.x) | ((unsigned)f2bf(v.y) << 16);
    o.y = (unsigned)f2bf(v.z) | ((unsigned)f2bf(v.w) << 16);
    ((uint2*)out)[i] = o;
  }
}

// ------------- transpose + convert: f32 [R][C] -> bf16 [C][R] -------------
__global__ void k_transpose_bf16(const float* __restrict__ in,
                                 unsigned short* __restrict__ out,
                                 int R, int C) {
  __shared__ float tile[64][65];
  int c0 = blockIdx.x * 64, r0 = blockIdx.y * 64;
  int t = threadIdx.x;
#pragma unroll
  for (int j = 0; j < 16; ++j) {
    int idx = t + j * 256;
    int rl = idx >> 6, cl = idx & 63;
    tile[rl][cl] = in[(size_t)(r0 + rl) * C + c0 + cl];
  }
  __syncthreads();
#pragma unroll
  for (int j = 0; j < 16; ++j) {
    int idx = t + j * 256;
    int cl = idx >> 6, rl = idx & 63;
    out[(size_t)(c0 + cl) * R + r0 + rl] = f2bf(tile[rl][cl]);
  }
}

// ---------------- bf16 GEMM: C[M][N] = A[M][K] * B^T, B stored [N][K] -----
// 128x128 tile, BK=64, 4 waves (2x2), 16x16x32 MFMA, global_load_lds + swizzle
template <bool OUT_BF16>
__global__ __launch_bounds__(256, 2) void k_gemm(
    const unsigned short* __restrict__ A, const unsigned short* __restrict__ B,
    void* __restrict__ Cout, int M, int N, int K) {
  __shared__ unsigned short sA[2][128 * 64];
  __shared__ unsigned short sB[2][128 * 64];
  const int t = threadIdx.x;
  const int lane = t & 63;
  const int wid = t >> 6;
  const int m0 = blockIdx.y * 128;
  const int n0 = blockIdx.x * 128;
  const int wr = wid >> 1, wc = wid & 1;
  const int lrow = lane & 15, lgrp = lane >> 4;

  f32x4 acc[4][4] = {};

  const int lr = lane >> 3;                    // 0..7  (row within 8-row group)
  const int sw = (lane & 7) ^ (lr & 7);        // swizzled logical chunk

  const int NT = K >> 6;

  auto stage = [&](int buf, int kt) {
    const int klo = kt * 64;
#pragma unroll
    for (int i = 0; i < 4; ++i) {
      int r = wid * 32 + i * 8 + lr;
      async_cp16(A + (size_t)(m0 + r) * K + klo + sw * 8,
                 &sA[buf][(wid * 32 + i * 8) * 64]);
    }
#pragma unroll
    for (int i = 0; i < 4; ++i) {
      int r = wid * 32 + i * 8 + lr;
      async_cp16(B + (size_t)(n0 + r) * K + klo + sw * 8,
                 &sB[buf][(wid * 32 + i * 8) * 64]);
    }
  };

  stage(0, 0);
  for (int kt = 0; kt < NT; ++kt) {
    int cur = kt & 1;
    __syncthreads();  // drains vmcnt(0): current buffer ready, other buffer free
    if (kt + 1 < NT) stage(cur ^ 1, kt + 1);
#pragma unroll
    for (int kk = 0; kk < 2; ++kk) {
      bf16x8 af[4], bfr[4];
#pragma unroll
      for (int m = 0; m < 4; ++m) {
        int r = wr * 64 + m * 16 + lrow;
        int c = (kk * 4 + lgrp) ^ (r & 7);
        af[m] = *(const bf16x8*)&sA[cur][r * 64 + c * 8];
      }
#pragma unroll
      for (int n = 0; n < 4; ++n) {
        int r = wc * 64 + n * 16 + lrow;
        int c = (kk * 4 + lgrp) ^ (r & 7);
        bfr[n] = *(const bf16x8*)&sB[cur][r * 64 + c * 8];
      }
#pragma unroll
      for (int m = 0; m < 4; ++m)
#pragma unroll
        for (int n = 0; n < 4; ++n)
          acc[m][n] = __builtin_amdgcn_mfma_f32_16x16x32_bf16(
              af[m], bfr[n], acc[m][n], 0, 0, 0);
    }
  }
#pragma unroll
  for (int m = 0; m < 4; ++m) {
    int row_b = m0 + wr * 64 + m * 16 + lgrp * 4;
#pragma unroll
    for (int n = 0; n < 4; ++n) {
      int col = n0 + wc * 64 + n * 16 + lrow;
#pragma unroll
      for (int r = 0; r < 4; ++r) {
        int row = row_b + r;
        if constexpr (OUT_BF16)
          ((unsigned short*)Cout)[(size_t)row * N + col] = f2bf(acc[m][n][r]);
        else
          ((float*)Cout)[(size_t)row * N + col] = acc[m][n][r];
      }
    }
  }
}

// ---------------- RoPE + layout: qkv[2048][8192] -> Q, K (roped), V^T -----
__global__ void k_rope_layout(const unsigned short* __restrict__ qkv,
                              const float* __restrict__ fcos,
                              const float* __restrict__ fsin,
                              unsigned short* __restrict__ Q,
                              unsigned short* __restrict__ K,
                              unsigned short* __restrict__ VT) {
  int s0 = blockIdx.x * 64;
  int y = blockIdx.y;
  int t = threadIdx.x;
  if (y < 24) {
    int colb = (y < 16) ? y * 256 : 4096 + (y - 16) * 256;
    unsigned short* out =
        (y < 16) ? (Q + (size_t)y * S_LEN * HDIM)
                 : (K + (size_t)(y - 16) * S_LEN * HDIM);
#pragma unroll 4
    for (int j = 0; j < 32; ++j) {
      int idx = t + j * 256;
      int sl = idx >> 7;
      int d = idx & 127;
      int s = s0 + sl;
      float x1 = bf2f(qkv[(size_t)s * QKV_N + colb + d]);
      float x2 = bf2f(qkv[(size_t)s * QKV_N + colb + d + 128]);
      float c = fcos[s * 128 + d], sn = fsin[s * 128 + d];
      out[(size_t)s * HDIM + d] = f2bf(x1 * c - x2 * sn);
      out[(size_t)s * HDIM + d + 128] = f2bf(x1 * sn + x2 * c);
    }
  } else {
    int kh = y - 24;
    __shared__ unsigned short tile[64][258];
#pragma unroll 4
    for (int j = 0; j < 64; ++j) {
      int idx = t + j * 256;
      int sl = idx >> 8;
      int d = idx & 255;
      tile[sl][d] = qkv[(size_t)(s0 + sl) * QKV_N + 6144 + kh * 256 + d];
    }
    __syncthreads();
#pragma unroll 4
    for (int j = 0; j < 64; ++j) {
      int idx = t + j * 256;
      int d = idx >> 6;
      int sl = idx & 63;
      VT[(size_t)kh * HDIM * S_LEN + (size_t)d * S_LEN + s0 + sl] = tile[sl][d];
    }
  }
}

// ---------------- windowed softcap attention --------------------------------
// Fixed softmax offset: post-softcap scores bounded by +/-50 -> exp(s-50).
// 2-way k-split: 4 waves/block; wave (sub, chunk) handles 16 q-rows (sub) and
// half the key range (chunk). Partials combined through LDS (add-only merge —
// fixed offset means no max bookkeeping). V prefetched into registers so its
// latency hides under QK+softmax.
__global__ __launch_bounds__(256, 2) void k_attn(
    const unsigned short* __restrict__ Q,   // [16][2048][256]
    const unsigned short* __restrict__ K,   // [8][2048][256]
    const unsigned short* __restrict__ VT,  // [8][256][2048]
    unsigned short* __restrict__ O) {       // [2048][4096]
  __shared__ unsigned short sP[4][16 * 48];
  __shared__ float sO[2][16][260];
  __shared__ float sPs[2][16];
  int t = threadIdx.x, lane = t & 63, w = t >> 6;
  int sub = w >> 1, chunk = w & 1;
  int h = blockIdx.y;
  int r0 = blockIdx.x * 32 + sub * 16;
  const unsigned short* Qh = Q + (size_t)h * S_LEN * HDIM;
  const unsigned short* Kh = K + (size_t)(h >> 1) * S_LEN * HDIM;
  const unsigned short* Vh = VT + (size_t)(h >> 1) * HDIM * S_LEN;
  const int lrow = lane & 15, lgrp = lane >> 4;

  bf16x8 qf[8];
#pragma unroll
  for (int dc = 0; dc < 8; ++dc)
    qf[dc] = *(const bf16x8*)&Qh[(size_t)(r0 + lrow) * HDIM + dc * 32 + lgrp * 8];

  f32x4 zero4 = {0.f, 0.f, 0.f, 0.f};
  f32x4 o[16];
#pragma unroll
  for (int i = 0; i < 16; ++i) o[i] = zero4;
  float psum[4] = {0.f, 0.f, 0.f, 0.f};

  int klo = r0 - (WINLEN - 1);
  if (klo < 0) klo = 0;
  klo &= ~31;
  const int N_it = ((r0 + 15 - klo) >> 5) + 1;  // 32-wide key steps
  const int half = (N_it + 1) >> 1;
  const int it_count = chunk ? (N_it - half) : half;
  const int k_begin = klo + (chunk ? half * 32 : 0);

  const float c_pre = 0.0625f / 50.0f;           // SCALING / SOFTCAP
  const float c_2l2e = 2.8853900817779268f;      // 2*log2(e)
  const float c_l2e = 1.4426950408889634f;
  unsigned short* myP = sP[w];

  for (int it = 0; it < it_count; ++it) {
    int k0 = k_begin + it * 32;
    // V prefetch: independent of QK/softmax, issued first so VMEM latency
    // hides under the compute below.
    bf16x8 vf[16];
#pragma unroll
    for (int dt = 0; dt < 16; ++dt)
      vf[dt] =
          *(const bf16x8*)&Vh[(size_t)(dt * 16 + lrow) * S_LEN + k0 + lgrp * 8];
#pragma unroll
    for (int st = 0; st < 2; ++st) {
      int ks = k0 + st * 16;
      // two 4-deep accumulator chains halve serial MFMA latency
      f32x4 sa = zero4, sb = zero4;
#pragma unroll
      for (int dc = 0; dc < 4; ++dc) {
        bf16x8 kfa =
            *(const bf16x8*)&Kh[(size_t)(ks + lrow) * HDIM + dc * 32 + lgrp * 8];
        bf16x8 kfb = *(const bf16x8*)&Kh[(size_t)(ks + lrow) * HDIM +
                                         (dc + 4) * 32 + lgrp * 8];
        sa = __builtin_amdgcn_mfma_f32_16x16x32_bf16(qf[dc], kfa, sa, 0, 0, 0);
        sb = __builtin_amdgcn_mfma_f32_16x16x32_bf16(qf[dc + 4], kfb, sb, 0, 0, 0);
      }
      f32x4 s = sa + sb;
#pragma unroll
      for (int r = 0; r < 4; ++r) {
        int q = r0 + lgrp * 4 + r;
        int k = ks + lrow;
        float tt = s[r] * c_pre;
        tt = fminf(fmaxf(tt, -10.f), 10.f);
        float z = fast_exp2(tt * c_2l2e);
        float sc = (z - 1.f) * fast_rcp(z + 1.f) * 50.f;
        float p = 0.f;
        if (k <= q && (q - k) < WINLEN)
          p = fast_exp2((sc - 50.f) * c_l2e);
        unsigned short pb = f2bf(p);
        psum[r] += bf2f(pb);
        myP[(lgrp * 4 + r) * 48 + st * 16 + lrow] = pb;
      }
    }
    bf16x8 pf = *(const bf16x8*)&myP[lrow * 48 + lgrp * 8];
#pragma unroll
    for (int dt = 0; dt < 16; ++dt)
      o[dt] = __builtin_amdgcn_mfma_f32_16x16x32_bf16(pf, vf[dt], o[dt], 0, 0, 0);
  }

  // per-row denominator totals (no inversion yet — partials must merge first)
#pragma unroll
  for (int r = 0; r < 4; ++r) {
    float v = psum[r];
    v += __shfl_xor(v, 1);
    v += __shfl_xor(v, 2);
    v += __shfl_xor(v, 4);
    v += __shfl_xor(v, 8);
    psum[r] = v;
  }

  if (chunk == 1) {
#pragma unroll
    for (int dt = 0; dt < 16; ++dt)
#pragma unroll
      for (int r = 0; r < 4; ++r)
        sO[sub][lgrp * 4 + r][dt * 16 + lrow] = o[dt][r];
    if (lrow == 0) {
#pragma unroll
      for (int r = 0; r < 4; ++r) sPs[sub][lgrp * 4 + r] = psum[r];
    }
  }
  __syncthreads();
  if (chunk == 0) {
    float inv[4];
#pragma unroll
    for (int r = 0; r < 4; ++r)
      inv[r] = 1.0f / (psum[r] + sPs[sub][lgrp * 4 + r]);
#pragma unroll
    for (int dt = 0; dt < 16; ++dt)
#pragma unroll
      for (int r = 0; r < 4; ++r) {
        int row = r0 + lgrp * 4 + r;
        float val = o[dt][r] + sO[sub][lgrp * 4 + r][dt * 16 + lrow];
        O[(size_t)row * AO_N + h * HDIM + dt * 16 + lrow] = f2bf(val * inv[r]);
      }
  }
}

extern "C" void kernel_launch(void* const* d_in, const int* in_sizes, int n_in,
                              void* d_out, int out_size, void* d_ws,
                              size_t ws_size, hipStream_t stream) {
  const float* hidden = (const float*)d_in[0];
  const float* Wqkv = (const float*)d_in[1];
  const float* Wo = (const float*)d_in[2];
  const float* fcos = (const float*)d_in[3];
  const float* fsin = (const float*)d_in[4];
  float* out = (float*)d_out;
  char* ws = (char*)d_ws;

  // workspace layout (bytes):
  // [0, 58720256)          WqkvT bf16 [8192][3584]; reused later for Q/K/VT
  // [58720256, 73400320)   hidden bf16 [2048][3584]
  // [73400320, 106954752)  qkv bf16 [2048][8192]; reused later for AttnOut
  // [106954752, 136314880) WoT bf16 [3584][4096]
  unsigned short* WqkvT = (unsigned short*)(ws + 0);
  unsigned short* hb = (unsigned short*)(ws + 58720256);
  unsigned short* qkv = (unsigned short*)(ws + 73400320);
  unsigned short* WoT = (unsigned short*)(ws + 106954752);
  unsigned short* Qb = WqkvT;                           // [16][2048][256]
  unsigned short* Kb = WqkvT + (size_t)16 * 2048 * 256; // [8][2048][256]
  unsigned short* VTb = WqkvT + (size_t)24 * 2048 * 256;// [8][256][2048]
  unsigned short* AO = qkv;                             // [2048][4096]

  k_cast_bf16<<<1024, 256, 0, stream>>>(hidden, hb, (2048 * 3584) / 4);
  k_transpose_bf16<<<dim3(8192 / 64, 3584 / 64), 256, 0, stream>>>(
      Wqkv, WqkvT, 3584, 8192);
  k_transpose_bf16<<<dim3(3584 / 64, 4096 / 64), 256, 0, stream>>>(
      Wo, WoT, 4096, 3584);
  k_gemm<true><<<dim3(64, 16), 256, 0, stream>>>(hb, WqkvT, qkv, 2048, 8192,
                                                 3584);
  k_rope_layout<<<dim3(32, 32), 256, 0, stream>>>(qkv, fcos, fsin, Qb, Kb, VTb);
  k_attn<<<dim3(64, 16), 256, 0, stream>>>(Qb, Kb, VTb, AO);
  k_gemm<false><<<dim3(28, 16), 256, 0, stream>>>(AO, WoT, out, 2048, 3584,
                                                  4096);
}

// Round 5
// 564.618 us; speedup vs baseline: 1.2975x; 1.2965x over previous
//
#include <hip/hip_runtime.h>
#include <hip/hip_bf16.h>
#include <stdint.h>

#define S_LEN 2048
#define HIDDEN 3584
#define NHEAD 16
#define NKVH 8
#define HDIM 256
#define QKV_N 8192
#define AO_N 4096
#define WINLEN 1024

typedef __attribute__((ext_vector_type(8))) short bf16x8;
typedef __attribute__((ext_vector_type(4))) float f32x4;

__device__ __forceinline__ void async_cp16(const void* g, void* l) {
  __builtin_amdgcn_global_load_lds(
      (const __attribute__((address_space(1))) void*)g,
      (__attribute__((address_space(3))) void*)l, 16, 0, 0);
}

__device__ __forceinline__ float fast_exp2(float x) {
#if __has_builtin(__builtin_amdgcn_exp2f)
  return __builtin_amdgcn_exp2f(x);
#else
  return __exp2f(x);
#endif
}
__device__ __forceinline__ float fast_rcp(float x) {
#if __has_builtin(__builtin_amdgcn_rcpf)
  return __builtin_amdgcn_rcpf(x);
#else
  return 1.0f / x;
#endif
}

__device__ __forceinline__ unsigned short f2bf(float f) {
  unsigned u = __float_as_uint(f);
  u += 0x7FFF + ((u >> 16) & 1);
  return (unsigned short)(u >> 16);
}
__device__ __forceinline__ float bf2f(unsigned short h) {
  return __uint_as_float(((unsigned)h) << 16);
}

// ---------------- elementwise f32 -> bf16 cast (vectorized) ----------------
__global__ void k_cast_bf16(const float* __restrict__ in,
                            unsigned short* __restrict__ out, int n4) {
  int i = blockIdx.x * blockDim.x + threadIdx.x;
  int stride = gridDim.x * blockDim.x;
  for (; i < n4; i += stride) {
    float4 v = ((const float4*)in)[i];
    uint2 o;
    o.x = (unsigned)f2bf(v.x) | ((unsigned)f2bf(v.y) << 16);
    o.y = (unsigned)f2bf(v.z) | ((unsigned)f2bf(v.w) << 16);
    ((uint2*)out)[i] = o;
  }
}

// ------------- transpose + convert: f32 [R][C] -> bf16 [C][R] -------------
__global__ void k_transpose_bf16(const float* __restrict__ in,
                                 unsigned short* __restrict__ out,
                                 int R, int C) {
  __shared__ float tile[64][65];
  int c0 = blockIdx.x * 64, r0 = blockIdx.y * 64;
  int t = threadIdx.x;
#pragma unroll
  for (int j = 0; j < 16; ++j) {
    int idx = t + j * 256;
    int rl = idx >> 6, cl = idx & 63;
    tile[rl][cl] = in[(size_t)(r0 + rl) * C + c0 + cl];
  }
  __syncthreads();
#pragma unroll
  for (int j = 0; j < 16; ++j) {
    int idx = t + j * 256;
    int cl = idx >> 6, rl = idx & 63;
    out[(size_t)(c0 + cl) * R + r0 + rl] = f2bf(tile[rl][cl]);
  }
}

// ---------------- bf16 GEMM: C[M][N] = A[M][K] * B^T, B stored [N][K] -----
template <bool OUT_BF16>
__global__ __launch_bounds__(256, 2) void k_gemm(
    const unsigned short* __restrict__ A, const unsigned short* __restrict__ B,
    void* __restrict__ Cout, int M, int N, int K) {
  __shared__ unsigned short sA[2][128 * 64];
  __shared__ unsigned short sB[2][128 * 64];
  const int t = threadIdx.x;
  const int lane = t & 63;
  const int wid = t >> 6;
  const int m0 = blockIdx.y * 128;
  const int n0 = blockIdx.x * 128;
  const int wr = wid >> 1, wc = wid & 1;
  const int lrow = lane & 15, lgrp = lane >> 4;

  f32x4 acc[4][4] = {};

  const int lr = lane >> 3;
  const int sw = (lane & 7) ^ (lr & 7);

  const int NT = K >> 6;

  auto stage = [&](int buf, int kt) {
    const int klo = kt * 64;
#pragma unroll
    for (int i = 0; i < 4; ++i) {
      int r = wid * 32 + i * 8 + lr;
      async_cp16(A + (size_t)(m0 + r) * K + klo + sw * 8,
                 &sA[buf][(wid * 32 + i * 8) * 64]);
    }
#pragma unroll
    for (int i = 0; i < 4; ++i) {
      int r = wid * 32 + i * 8 + lr;
      async_cp16(B + (size_t)(n0 + r) * K + klo + sw * 8,
                 &sB[buf][(wid * 32 + i * 8) * 64]);
    }
  };

  stage(0, 0);
  for (int kt = 0; kt < NT; ++kt) {
    int cur = kt & 1;
    __syncthreads();
    if (kt + 1 < NT) stage(cur ^ 1, kt + 1);
#pragma unroll
    for (int kk = 0; kk < 2; ++kk) {
      bf16x8 af[4], bfr[4];
#pragma unroll
      for (int m = 0; m < 4; ++m) {
        int r = wr * 64 + m * 16 + lrow;
        int c = (kk * 4 + lgrp) ^ (r & 7);
        af[m] = *(const bf16x8*)&sA[cur][r * 64 + c * 8];
      }
#pragma unroll
      for (int n = 0; n < 4; ++n) {
        int r = wc * 64 + n * 16 + lrow;
        int c = (kk * 4 + lgrp) ^ (r & 7);
        bfr[n] = *(const bf16x8*)&sB[cur][r * 64 + c * 8];
      }
#pragma unroll
      for (int m = 0; m < 4; ++m)
#pragma unroll
        for (int n = 0; n < 4; ++n)
          acc[m][n] = __builtin_amdgcn_mfma_f32_16x16x32_bf16(
              af[m], bfr[n], acc[m][n], 0, 0, 0);
    }
  }
#pragma unroll
  for (int m = 0; m < 4; ++m) {
    int row_b = m0 + wr * 64 + m * 16 + lgrp * 4;
#pragma unroll
    for (int n = 0; n < 4; ++n) {
      int col = n0 + wc * 64 + n * 16 + lrow;
#pragma unroll
      for (int r = 0; r < 4; ++r) {
        int row = row_b + r;
        if constexpr (OUT_BF16)
          ((unsigned short*)Cout)[(size_t)row * N + col] = f2bf(acc[m][n][r]);
        else
          ((float*)Cout)[(size_t)row * N + col] = acc[m][n][r];
      }
    }
  }
}

// ---------------- RoPE + layout: qkv[2048][8192] -> Q, K (roped), VTblk ----
// VTblk layout: [kvh][k/64][256 d][64 k]  (each 64-key V^T tile contiguous)
__global__ void k_rope_layout(const unsigned short* __restrict__ qkv,
                              const float* __restrict__ fcos,
                              const float* __restrict__ fsin,
                              unsigned short* __restrict__ Q,
                              unsigned short* __restrict__ K,
                              unsigned short* __restrict__ VT) {
  int s0 = blockIdx.x * 64;
  int y = blockIdx.y;
  int t = threadIdx.x;
  if (y < 24) {
    int colb = (y < 16) ? y * 256 : 4096 + (y - 16) * 256;
    unsigned short* out =
        (y < 16) ? (Q + (size_t)y * S_LEN * HDIM)
                 : (K + (size_t)(y - 16) * S_LEN * HDIM);
#pragma unroll 4
    for (int j = 0; j < 32; ++j) {
      int idx = t + j * 256;
      int sl = idx >> 7;
      int d = idx & 127;
      int s = s0 + sl;
      float x1 = bf2f(qkv[(size_t)s * QKV_N + colb + d]);
      float x2 = bf2f(qkv[(size_t)s * QKV_N + colb + d + 128]);
      float c = fcos[s * 128 + d], sn = fsin[s * 128 + d];
      out[(size_t)s * HDIM + d] = f2bf(x1 * c - x2 * sn);
      out[(size_t)s * HDIM + d + 128] = f2bf(x1 * sn + x2 * c);
    }
  } else {
    int kh = y - 24;
    __shared__ unsigned short tile[64][258];
#pragma unroll 4
    for (int j = 0; j < 64; ++j) {
      int idx = t + j * 256;
      int sl = idx >> 8;
      int d = idx & 255;
      tile[sl][d] = qkv[(size_t)(s0 + sl) * QKV_N + 6144 + kh * 256 + d];
    }
    __syncthreads();
    size_t base = (size_t)kh * HDIM * S_LEN + (size_t)(s0 >> 6) * (HDIM * 64);
#pragma unroll 4
    for (int j = 0; j < 64; ++j) {
      int idx = t + j * 256;
      int d = idx >> 6;
      int sl = idx & 63;
      VT[base + idx] = tile[sl][d];
    }
  }
}

// ---------------- windowed softcap attention (LDS-staged, cooperative) ------
// Block: 64 q-rows x 1 head, 4 waves (16 q-rows each) sharing K/V LDS tiles.
// K-step 64. K tile [64][256] + V^T tile [256][64] staged via global_load_lds
// (coalesced 128B, XOR-swizzled via pre-swizzled source). Fixed softmax
// offset exp(s-50): no running max.
__global__ __launch_bounds__(256, 2) void k_attn(
    const unsigned short* __restrict__ Q,    // [16][2048][256]
    const unsigned short* __restrict__ K,    // [8][2048][256]
    const unsigned short* __restrict__ VTB,  // [8][32][256][64] blocked V^T
    unsigned short* __restrict__ O) {        // [2048][4096]
  __shared__ unsigned short sK[64 * 256];    // 32 KB
  __shared__ unsigned short sV[256 * 64];    // 32 KB
  __shared__ unsigned short sP[4][16 * 64];  // 8 KB (per-wave P tiles)
  const int t = threadIdx.x, lane = t & 63, w = t >> 6;
  const int h = blockIdx.y;
  const int r0b = blockIdx.x * 64;
  const int r0w = r0b + w * 16;
  const int lrow = lane & 15, lgrp = lane >> 4;
  const unsigned short* Qh = Q + (size_t)h * S_LEN * HDIM;
  const char* KhB = (const char*)(K + (size_t)(h >> 1) * S_LEN * HDIM);
  const char* VbB = (const char*)(VTB + (size_t)(h >> 1) * S_LEN * HDIM);

  // staging source offsets (swizzle on source, linear LDS dest — m173 pattern)
  // K: row' = t>>5 (low 3 bits of row), chunk c = t&31 of 32x16B per 512B row
  const int cK = t & 31;
  const int rK = t >> 5;
  const int csK = (cK & 24) | ((cK ^ rK) & 7);
  const int ksrcoff = rK * 512 + csK * 16;  // + k0*512 + rr*4096
  // V: d' = t>>3 (low bits of d), chunk c = t&7 of 8x16B per 128B row
  const int csV = (t & 7) ^ ((t >> 3) & 7);
  const int vsrcoff = (t >> 3) * 128 + csV * 16;  // + kb*32768 + rr*4096

  bf16x8 qf[8];
#pragma unroll
  for (int dc = 0; dc < 8; ++dc)
    qf[dc] =
        *(const bf16x8*)&Qh[(size_t)(r0w + lrow) * HDIM + dc * 32 + lgrp * 8];

  f32x4 zero4 = {0.f, 0.f, 0.f, 0.f};
  f32x4 o[16];
#pragma unroll
  for (int i = 0; i < 16; ++i) o[i] = zero4;
  float psum[4] = {0.f, 0.f, 0.f, 0.f};

  const int klo = (r0b >= 1024) ? (r0b - 1024) : 0;
  const int nsteps = ((r0b - klo) >> 6) + 1;

  const float c_pre = 0.0625f / 50.0f;       // SCALING / SOFTCAP
  const float c_2l2e = 2.8853900817779268f;  // 2*log2(e)
  const float c_l2e = 1.4426950408889634f;
  unsigned short* myP = sP[w];

  for (int step = 0; step < nsteps; ++step) {
    const int k0 = klo + step * 64;
    __syncthreads();  // previous step's compute done; LDS free
    {
      const char* ks = KhB + (size_t)k0 * 512;
      const char* vs = VbB + (size_t)(k0 >> 6) * 32768;
      char* dK = (char*)sK + t * 16;
      char* dV = (char*)sV + t * 16;
#pragma unroll
      for (int rr = 0; rr < 8; ++rr)
        async_cp16(ks + ksrcoff + rr * 4096, dK + rr * 4096);
#pragma unroll
      for (int rr = 0; rr < 8; ++rr)
        async_cp16(vs + vsrcoff + rr * 4096, dV + rr * 4096);
    }
    __syncthreads();  // vmcnt(0) drained before barrier: tiles ready

    // ---- QK^T + softcap + mask + exp (P into per-wave LDS tile) ----
#pragma unroll
    for (int st = 0; st < 4; ++st) {
      const int row = st * 16 + lrow;
      const int rs7 = lrow & 7;
      f32x4 sa = zero4, sb = zero4;
#pragma unroll
      for (int dc = 0; dc < 4; ++dc) {
        const int La = dc * 4 + lgrp;
        const int Lb = (dc + 4) * 4 + lgrp;
        bf16x8 kfa = *(const bf16x8*)&sK[row * 256 +
                                         ((La & 24) | ((La ^ rs7) & 7)) * 8];
        bf16x8 kfb = *(const bf16x8*)&sK[row * 256 +
                                         ((Lb & 24) | ((Lb ^ rs7) & 7)) * 8];
        sa = __builtin_amdgcn_mfma_f32_16x16x32_bf16(qf[dc], kfa, sa, 0, 0, 0);
        sb = __builtin_amdgcn_mfma_f32_16x16x32_bf16(qf[dc + 4], kfb, sb, 0, 0,
                                                     0);
      }
      f32x4 s = sa + sb;
#pragma unroll
      for (int r = 0; r < 4; ++r) {
        const int q = r0w + lgrp * 4 + r;
        const int k = k0 + st * 16 + lrow;
        float tt = s[r] * c_pre;
        tt = fminf(fmaxf(tt, -10.f), 10.f);
        float z = fast_exp2(tt * c_2l2e);
        float sc = (z - 1.f) * fast_rcp(z + 1.f) * 50.f;
        float p = 0.f;
        if (k <= q && (q - k) < WINLEN)
          p = fast_exp2((sc - 50.f) * c_l2e);
        unsigned short pb = f2bf(p);
        psum[r] += bf2f(pb);
        const int qrow = lgrp * 4 + r;
        const int cc = st * 2 + (lrow >> 3);
        myP[qrow * 64 + (cc ^ (qrow & 7)) * 8 + (lrow & 7)] = pb;
      }
    }

    // ---- PV (A from own-wave P tile, B from shared V tile) ----
#pragma unroll
    for (int ks2 = 0; ks2 < 2; ++ks2) {
      const int cc = ks2 * 4 + lgrp;
      bf16x8 pf = *(const bf16x8*)&myP[lrow * 64 + (cc ^ (lrow & 7)) * 8];
#pragma unroll
      for (int dt = 0; dt < 16; ++dt) {
        const int d = dt * 16 + lrow;
        bf16x8 vf = *(const bf16x8*)&sV[d * 64 + (cc ^ (lrow & 7)) * 8];
        o[dt] = __builtin_amdgcn_mfma_f32_16x16x32_bf16(pf, vf, o[dt], 0, 0, 0);
      }
    }
  }

  // ---- denominators + write ----
#pragma unroll
  for (int r = 0; r < 4; ++r) {
    float v = psum[r];
    v += __shfl_xor(v, 1);
    v += __shfl_xor(v, 2);
    v += __shfl_xor(v, 4);
    v += __shfl_xor(v, 8);
    psum[r] = 1.0f / v;
  }
#pragma unroll
  for (int dt = 0; dt < 16; ++dt)
#pragma unroll
    for (int r = 0; r < 4; ++r) {
      int row = r0w + lgrp * 4 + r;
      O[(size_t)row * AO_N + h * HDIM + dt * 16 + lrow] =
          f2bf(o[dt][r] * psum[r]);
    }
}

extern "C" void kernel_launch(void* const* d_in, const int* in_sizes, int n_in,
                              void* d_out, int out_size, void* d_ws,
                              size_t ws_size, hipStream_t stream) {
  const float* hidden = (const float*)d_in[0];
  const float* Wqkv = (const float*)d_in[1];
  const float* Wo = (const float*)d_in[2];
  const float* fcos = (const float*)d_in[3];
  const float* fsin = (const float*)d_in[4];
  float* out = (float*)d_out;
  char* ws = (char*)d_ws;

  unsigned short* WqkvT = (unsigned short*)(ws + 0);
  unsigned short* hb = (unsigned short*)(ws + 58720256);
  unsigned short* qkv = (unsigned short*)(ws + 73400320);
  unsigned short* WoT = (unsigned short*)(ws + 106954752);
  unsigned short* Qb = WqkvT;                            // [16][2048][256]
  unsigned short* Kb = WqkvT + (size_t)16 * 2048 * 256;  // [8][2048][256]
  unsigned short* VTb = WqkvT + (size_t)24 * 2048 * 256; // [8][32][256][64]
  unsigned short* AO = qkv;                              // [2048][4096]

  k_cast_bf16<<<1024, 256, 0, stream>>>(hidden, hb, (2048 * 3584) / 4);
  k_transpose_bf16<<<dim3(8192 / 64, 3584 / 64), 256, 0, stream>>>(
      Wqkv, WqkvT, 3584, 8192);
  k_transpose_bf16<<<dim3(3584 / 64, 4096 / 64), 256, 0, stream>>>(
      Wo, WoT, 4096, 3584);
  k_gemm<true><<<dim3(64, 16), 256, 0, stream>>>(hb, WqkvT, qkv, 2048, 8192,
                                                 3584);
  k_rope_layout<<<dim3(32, 32), 256, 0, stream>>>(qkv, fcos, fsin, Qb, Kb, VTb);
  k_attn<<<dim3(32, 16), 256, 0, stream>>>(Qb, Kb, VTb, AO);
  k_gemm<false><<<dim3(28, 16), 256, 0, stream>>>(AO, WoT, out, 2048, 3584,
                                                  4096);
}